// Round 1
// baseline (1505.553 us; speedup 1.0000x reference)
//
#include <hip/hip_runtime.h>

// EquivariantLayerBlock: X[512][512][1024] fp32 -> Y[1024][512] fp32, 10 scalar weights.
// Y[c,j] = w0*S2[c] + w1*D[c] + w2*A1[c,j] + w3*A0[c,j] + w4*X[j,j,c]
//        + w5*total + w6*diag_total + w7*R0[j] + w8*R1[j] + w9*Dg[j]
// A1[c,j]=sum_b X[j,b,c], A0[c,j]=sum_a X[a,j,c], S2[c]=sum_{a,b}, D[c]=diag col sum,
// R0[j]=sum_{b,c}X[j,b,c], R1[j]=sum_{a,c}X[a,j,c], Dg[j]=sum_c X[j,j,c].

#define N0 1024   // c, contiguous
#define N1 512    // a, b

#define TBK 32    // b per block
#define NBB 16    // b chunks
#define TAK 32    // a per block (8 per wave -> only 32 VGPR of A1 accumulators)
#define NAB 16    // a chunks
#define NCB 4     // c quarters
#define BG  4     // b per cross-wave reduce group

typedef float f4 __attribute__((ext_vector_type(4)));

// ws float offsets
#define OFF_A1P 0u                                   // [16][512][1024] b-chunk partials of A1
#define OFF_A0P (16u*512u*1024u)                     // [16][512][1024] a-chunk partials of A0
#define OFF_A1S (OFF_A0P + 16u*512u*1024u)           // [512 a][1024 c]
#define OFF_A0S (OFF_A1S + 512u*1024u)               // [512 b][1024 c]
#define OFF_D   (OFF_A0S + 512u*1024u)
#define OFF_R0  (OFF_D + 1024u)
#define OFF_R1  (OFF_R0 + 512u)
#define OFF_DG  (OFF_R1 + 512u)

// ---------- K1: streaming pass over X (1 GiB) ----------
// grid 1024 = cb(4) x bb(16) x ab(16); 256 threads; 4 blocks/CU (16 waves/CU).
// Wave w owns a = ab*32 + w*8 + i (i<8): holds A1 accumulators (32 VGPR),
// per-b A0 sums are cross-wave reduced in groups of BG=4.
__global__ __launch_bounds__(256, 4) void k1_stream(const f4* __restrict__ Xv,
                                                    float* __restrict__ ws) {
    f4* a1p = (f4*)(ws + OFF_A1P);
    f4* a0p = (f4*)(ws + OFF_A0P);

    const int id  = blockIdx.x;
    const int cb = id & 3;
    const int bb = (id >> 2) & 15;
    const int ab = id >> 6;
    const int tid = threadIdx.x;
    const int w = tid >> 6;
    const int l = tid & 63;
    const int c4 = cb * 64 + l;        // float4 index into the 256-f4 row
    const int b0 = bb * TBK;
    const int a0w = ab * TAK + w * 8;  // wave's 8 consecutive a

    f4 acc[8];
#pragma unroll
    for (int i = 0; i < 8; i++) acc[i] = (f4){0.f, 0.f, 0.f, 0.f};

    __shared__ f4 lred[3][BG][64];

    const f4* pw = Xv + ((size_t)a0w * N1 + b0) * (N0 / 4) + c4;

    for (int g = 0; g < TBK / BG; g++) {
        f4 s[BG];
#pragma unroll
        for (int q = 0; q < BG; q++) s[q] = (f4){0.f, 0.f, 0.f, 0.f};
#pragma unroll
        for (int i = 0; i < 8; i++) {
#pragma unroll
            for (int q = 0; q < BG; q++) {
                f4 v = __builtin_nontemporal_load(
                    pw + (size_t)i * N1 * (N0 / 4) + (size_t)(g * BG + q) * (N0 / 4));
                acc[i] += v;            // A1: per-a sum over b
                s[q] += v;              // A0: wave-partial sum over 8 a
            }
        }
        if (w > 0) {
#pragma unroll
            for (int q = 0; q < BG; q++) lred[w - 1][q][l] = s[q];
        }
        __syncthreads();
        if (w == 0) {
#pragma unroll
            for (int q = 0; q < BG; q++) {
                f4 t = s[q] + lred[0][q][l] + lred[1][q][l] + lred[2][q][l];
                a0p[((size_t)ab * N1 + (b0 + g * BG + q)) * (N0 / 4) + c4] = t;
            }
        }
        __syncthreads();
    }
#pragma unroll
    for (int i = 0; i < 8; i++)
        a1p[((size_t)bb * N1 + (a0w + i)) * (N0 / 4) + c4] = acc[i];
}

// ---------- K2: reduce partial chunks -> A1S/A0S + R0/R1, plus D and Dg ----------
// grid 1156: [0,512) a-pass, [512,1024) b-pass, [1024,1028) D, [1028,1156) Dg.
__global__ __launch_bounds__(256) void k2_reduce(const float* __restrict__ X,
                                                 float* __restrict__ ws) {
    const int tid = threadIdx.x;
    const int blk = blockIdx.x;
    __shared__ float red[256];
    if (blk < 2 * N1) {
        const bool ap = blk < N1;
        const int r = ap ? blk : blk - N1;
        const f4* pp = (const f4*)(ws + (ap ? OFF_A1P : OFF_A0P));
        f4 s = (f4){0.f, 0.f, 0.f, 0.f};
#pragma unroll
        for (int t = 0; t < 16; t++)
            s += __builtin_nontemporal_load(&pp[((size_t)t * N1 + r) * (N0 / 4) + tid]);
        ((f4*)(ws + (ap ? OFF_A1S : OFF_A0S)))[(size_t)r * (N0 / 4) + tid] = s;
        red[tid] = s[0] + s[1] + s[2] + s[3];
        __syncthreads();
        for (int st = 128; st; st >>= 1) { if (tid < st) red[tid] += red[tid + st]; __syncthreads(); }
        if (tid == 0) ws[(ap ? OFF_R0 : OFF_R1) + r] = red[0];
    } else if (blk < 2 * N1 + 4) {       // D[c] = sum_j X[j,j,c]
        const int c = (blk - 2 * N1) * 256 + tid;
        float sD = 0.f;
        for (int j = 0; j < N1; j++) sD += X[(size_t)j * (N1 * N0 + N0) + c];
        ws[OFF_D + c] = sD;
    } else {                             // Dg[j] = sum_c X[j,j,c]
        const int jb = (blk - (2 * N1 + 4)) * 4;
        for (int r2 = 0; r2 < 4; r2++) {
            const int j = jb + r2;
            const float* row = X + (size_t)j * (N1 * N0 + N0);
            float pr = row[tid] + row[tid + 256] + row[tid + 512] + row[tid + 768];
            red[tid] = pr;
            __syncthreads();
            for (int st = 128; st; st >>= 1) { if (tid < st) red[tid] += red[tid + st]; __syncthreads(); }
            if (tid == 0) ws[OFF_DG + j] = red[0];
            __syncthreads();
        }
    }
}

// ---------- K4: combine + transpose-write Y ----------
// 128 blocks (16 c-tiles x 8 j-tiles), 256 threads, 64x64 output tile.
// total = sum R0, diag_total = sum Dg, S2[c-tile] recomputed from L2-hot A1S.
__global__ __launch_bounds__(256) void k4_combine(const float* __restrict__ X,
                                                  const float* __restrict__ W,
                                                  const float* __restrict__ ws,
                                                  float* __restrict__ Y) {
    const float* A1S = ws + OFF_A1S;
    const float* A0S = ws + OFF_A0S;
    const float* D  = ws + OFF_D;
    const float* R0 = ws + OFF_R0;
    const float* R1 = ws + OFF_R1;
    const float* Dg = ws + OFF_DG;

    const int tid = threadIdx.x;
    const int ct = blockIdx.x & 15;
    const int jt = blockIdx.x >> 4;
    const int c0 = ct * 64, j0 = jt * 64;

    __shared__ float red[256];
    red[tid] = R0[tid] + R0[tid + 256];
    __syncthreads();
    for (int s = 128; s; s >>= 1) { if (tid < s) red[tid] += red[tid + s]; __syncthreads(); }
    const float total = red[0]; __syncthreads();
    red[tid] = Dg[tid] + Dg[tid + 256];
    __syncthreads();
    for (int s = 128; s; s >>= 1) { if (tid < s) red[tid] += red[tid + s]; __syncthreads(); }
    const float diag_total = red[0]; __syncthreads();

    const float w0 = W[0], w1 = W[1], w2 = W[2], w3 = W[3], w4 = W[4];
    const float w5 = W[5], w6 = W[6], w7 = W[7], w8 = W[8], w9 = W[9];

    const int cl = tid & 63;
    const int jr = tid >> 6;
    const int c = c0 + cl;

    // S2[c] = sum_a A1S[a][c] for this block's 64 c (A1S is 2 MB, L2-hot)
    float s2p = 0.f;
    const float* col = A1S + (size_t)jr * 128 * N0 + c;
#pragma unroll 8
    for (int a = 0; a < 128; a++) s2p += col[(size_t)a * N0];
    __shared__ float s2sh[4][64];
    s2sh[jr][cl] = s2p;
    __syncthreads();
    const float S2c = s2sh[0][cl] + s2sh[1][cl] + s2sh[2][cl] + s2sh[3][cl];

    const float base_c = w0 * S2c + w1 * D[c] + w5 * total + w6 * diag_total;

    __shared__ float T[64][65];
#pragma unroll
    for (int m = 0; m < 16; m++) {
        const int jo = jr * 16 + m;
        const int j = j0 + jo;
        const float a1 = A1S[(size_t)j * N0 + c];
        const float a0v = A0S[(size_t)j * N0 + c];
        const float dgv = X[(size_t)j * (N1 * N0 + N0) + c];
        const float y = base_c + w2 * a1 + w3 * a0v + w4 * dgv
                      + w7 * R0[j] + w8 * R1[j] + w9 * Dg[j];
        T[jo][cl] = y;
    }
    __syncthreads();
#pragma unroll
    for (int m = 0; m < 16; m++) {
        const int crow = jr * 16 + m;
        Y[(size_t)(c0 + crow) * N1 + (j0 + cl)] = T[cl][crow];
    }
}

extern "C" void kernel_launch(void* const* d_in, const int* in_sizes, int n_in,
                              void* d_out, int out_size, void* d_ws, size_t ws_size,
                              hipStream_t stream) {
    const float* X = (const float*)d_in[0];
    const float* W = (const float*)d_in[1];
    float* Y = (float*)d_out;
    float* ws = (float*)d_ws;

    k1_stream<<<NCB * NBB * NAB, 256, 0, stream>>>((const f4*)X, ws);
    k2_reduce<<<2 * N1 + 4 + N1 / 4, 256, 0, stream>>>(X, ws);
    k4_combine<<<16 * 8, 256, 0, stream>>>(X, W, ws, Y);
}